// Round 3
// baseline (373.360 us; speedup 1.0000x reference)
//
#include <hip/hip_runtime.h>
#include <math.h>

#define N_NODES 100000
#define N_EDGES 1600000
#define D_FEAT 64
#define EPS 1e-7f
#define NPART 8
#define COLS_PER_PART (N_NODES / NPART)   // 12500
#define QSCALE 12000.0f                   // ex in (0.367, 2.722) -> q in (4407, 32660) < 2^15
#define QINV (1.0f / 12000.0f)

typedef _Float16 h2 __attribute__((ext_vector_type(2)));

__device__ __forceinline__ unsigned pack2h(float a, float b) {
    h2 h;
    h.x = (_Float16)a;
    h.y = (_Float16)b;
    return __builtin_bit_cast(unsigned, h);
}

__device__ __forceinline__ float dot2acc(unsigned a, unsigned b, float c) {
#if __has_builtin(__builtin_amdgcn_fdot2)
    return __builtin_amdgcn_fdot2(__builtin_bit_cast(h2, a),
                                  __builtin_bit_cast(h2, b), c, false);
#else
    h2 ha = __builtin_bit_cast(h2, a), hb = __builtin_bit_cast(h2, b);
    return c + (float)ha.x * (float)hb.x + (float)ha.y * (float)hb.y;
#endif
}

__device__ __forceinline__ void fma2h(unsigned ab, float p, float& x, float& y) {
    h2 h = __builtin_bit_cast(h2, ab);
    x += p * (float)h.x;
    y += p * (float)h.y;
}

__device__ __forceinline__ float fastrcp(float x) {
#if __has_builtin(__builtin_amdgcn_rcpf)
    return __builtin_amdgcn_rcpf(x);
#else
    return 1.0f / x;
#endif
}

// Fused: blocks [0, norm_blocks) write raw-f16 x AND unit-normalized-f16 x
// (grid-stride, 16 lanes/node); blocks [norm_blocks, ...) do the
// XCD-partitioned col histogram (int4 reads).
__global__ void prep_kernel(const float4* __restrict__ x4, uint2* __restrict__ xh2,
                            uint2* __restrict__ xn2, const int* __restrict__ col,
                            unsigned* __restrict__ cnt, int norm_blocks) {
    if ((int)blockIdx.x < norm_blocks) {
        int stride = norm_blocks * blockDim.x;   // multiple of 16
        for (int tid = blockIdx.x * blockDim.x + threadIdx.x; tid < N_NODES * 16; tid += stride) {
            int node = tid >> 4;
            int lane = tid & 15;
            float4 v = x4[(size_t)node * 16 + lane];
            uint2 h;
            h.x = pack2h(v.x, v.y);
            h.y = pack2h(v.z, v.w);
            xh2[(size_t)node * 16 + lane] = h;
            float s = v.x * v.x + v.y * v.y + v.z * v.z + v.w * v.w;
            s += __shfl_xor(s, 1);
            s += __shfl_xor(s, 2);
            s += __shfl_xor(s, 4);
            s += __shfl_xor(s, 8);
            float rn = rsqrtf(s);    // ||x|| > 0 a.s.; EPS negligible (||A||||B|| ~ 64)
            uint2 hn;
            hn.x = pack2h(v.x * rn, v.y * rn);
            hn.y = pack2h(v.z * rn, v.w * rn);
            xn2[(size_t)node * 16 + lane] = hn;
        }
    } else {
        int hb = blockIdx.x - norm_blocks;
        int part = hb & (NPART - 1);           // consistent partition->XCD bijection
        int blk = hb >> 3;
        int nblk = (gridDim.x - norm_blocks) >> 3;
        int lo = part * COLS_PER_PART;
        int hi = lo + COLS_PER_PART;
        int stride = nblk * blockDim.x;
        const int4* col4 = (const int4*)col;
        for (int e = blk * blockDim.x + threadIdx.x; e < (N_EDGES >> 2); e += stride) {
            int4 c = col4[e];
            if (c.x >= lo && c.x < hi) atomicAdd(&cnt[c.x], 1u);
            if (c.y >= lo && c.y < hi) atomicAdd(&cnt[c.y], 1u);
            if (c.z >= lo && c.z < hi) atomicAdd(&cnt[c.z], 1u);
            if (c.w >= lo && c.w < hi) atomicAdd(&cnt[c.w], 1u);
        }
    }
}

// ---- hierarchical exclusive scan over cnt[0..N) -> offs, cursor ----
#define SCAN_B 256
__global__ void scan1_kernel(const unsigned* __restrict__ cnt, unsigned* __restrict__ incl,
                             unsigned* __restrict__ bsum) {
    __shared__ unsigned sh[SCAN_B];
    int i = blockIdx.x * SCAN_B + threadIdx.x;
    unsigned v = (i < N_NODES) ? cnt[i] : 0u;
    sh[threadIdx.x] = v;
    __syncthreads();
    for (int off = 1; off < SCAN_B; off <<= 1) {
        unsigned u = (threadIdx.x >= off) ? sh[threadIdx.x - off] : 0u;
        __syncthreads();
        sh[threadIdx.x] += u;
        __syncthreads();
    }
    if (i < N_NODES) incl[i] = sh[threadIdx.x];
    if (threadIdx.x == SCAN_B - 1) bsum[blockIdx.x] = sh[SCAN_B - 1];
}

__global__ void scan2_kernel(unsigned* __restrict__ bsum, int nblocks) {
    __shared__ unsigned sh[512];
    int t = threadIdx.x;
    unsigned v = (t < nblocks) ? bsum[t] : 0u;
    sh[t] = v;
    __syncthreads();
    for (int off = 1; off < 512; off <<= 1) {
        unsigned u = (t >= off) ? sh[t - off] : 0u;
        __syncthreads();
        sh[t] += u;
        __syncthreads();
    }
    if (t < nblocks) bsum[t] = sh[t] - v;  // exclusive
}

__global__ void scan3_kernel(const unsigned* __restrict__ cnt, const unsigned* __restrict__ incl,
                             const unsigned* __restrict__ bsum, unsigned* __restrict__ offs,
                             unsigned* __restrict__ cursor) {
    int i = blockIdx.x * SCAN_B + threadIdx.x;
    if (i < N_NODES) {
        unsigned o = bsum[blockIdx.x] + incl[i] - cnt[i];
        offs[i] = o;
        cursor[i] = o;
    } else if (i == N_NODES) {
        offs[N_NODES] = N_EDGES;
    }
}

// XCD-partitioned binning: block b serves col-partition (b & 7). Writes
// pay[pos] = row << 15 (low 15 bits filled by sim_csr_kernel later).
__global__ void place_kernel(const int* __restrict__ row, const int* __restrict__ col,
                             unsigned* __restrict__ cursor, unsigned* __restrict__ pay) {
    int part = blockIdx.x & (NPART - 1);
    int blk  = blockIdx.x >> 3;
    int nblk = gridDim.x >> 3;
    int lo = part * COLS_PER_PART;
    int hi = lo + COLS_PER_PART;
    int stride = nblk * blockDim.x;
    const int4* col4 = (const int4*)col;
    for (int e4 = blk * blockDim.x + threadIdx.x; e4 < (N_EDGES >> 2); e4 += stride) {
        int4 c = col4[e4];
        int e = e4 << 2;
        if (c.x >= lo && c.x < hi) {
            unsigned pos = atomicAdd(&cursor[c.x], 1u);
            pay[pos] = (unsigned)row[e] << 15;
        }
        if (c.y >= lo && c.y < hi) {
            unsigned pos = atomicAdd(&cursor[c.y], 1u);
            pay[pos] = (unsigned)row[e + 1] << 15;
        }
        if (c.z >= lo && c.z < hi) {
            unsigned pos = atomicAdd(&cursor[c.z], 1u);
            pay[pos] = (unsigned)row[e + 2] << 15;
        }
        if (c.w >= lo && c.w < hi) {
            unsigned pos = atomicAdd(&cursor[c.w], 1u);
            pay[pos] = (unsigned)row[e + 3] << 15;
        }
    }
}

// Persistent grid-stride waves: each 64-lane wave serially processes ~12
// nodes (amortizes WG dispatch; evens Poisson(16) degree imbalance).
// Per node: 32 edges per iter (8 sub-groups x 4 slots); pre-normalized f16
// features so ex = exp(beta * cos) with no norm gathers/divide; coalesced
// pay load redistributed via shuffles.
__global__ void sim_csr_kernel(const uint4* __restrict__ xn4, const unsigned* __restrict__ offs,
                               unsigned* __restrict__ pay, const float* __restrict__ beta_p,
                               float* __restrict__ segsum) {
    int lane = threadIdx.x & 63;
    int wid = (blockIdx.x * blockDim.x + threadIdx.x) >> 6;
    int nw = (gridDim.x * blockDim.x) >> 6;
    int sub = lane >> 3;      // 0..7
    int fl  = lane & 7;       // feature chunk: 8 f16 per lane
    float beta = beta_p[0];
    for (int node = wid; node < N_NODES; node += nw) {
        uint4 hc = xn4[(size_t)node * 8 + fl];
        int start = (int)offs[node];
        int end = (int)offs[node + 1];
        for (int i0 = start; i0 < end; i0 += 32) {
            int idx = i0 + lane;
            if (idx > end - 1) idx = end - 1;      // duplicate last edge: dedup'd
            unsigned pvL = pay[idx];               // coalesced
            unsigned pv0 = __shfl(pvL, sub);
            unsigned pv1 = __shfl(pvL, sub + 8);
            unsigned pv2 = __shfl(pvL, sub + 16);
            unsigned pv3 = __shfl(pvL, sub + 24);
            uint4 A0 = xn4[(size_t)(pv0 >> 15) * 8 + fl];
            uint4 A1 = xn4[(size_t)(pv1 >> 15) * 8 + fl];
            uint4 A2 = xn4[(size_t)(pv2 >> 15) * 8 + fl];
            uint4 A3 = xn4[(size_t)(pv3 >> 15) * 8 + fl];
            float d0 = 0.0f, d1 = 0.0f, d2 = 0.0f, d3 = 0.0f;
            d0 = dot2acc(A0.x, hc.x, d0); d1 = dot2acc(A1.x, hc.x, d1);
            d2 = dot2acc(A2.x, hc.x, d2); d3 = dot2acc(A3.x, hc.x, d3);
            d0 = dot2acc(A0.y, hc.y, d0); d1 = dot2acc(A1.y, hc.y, d1);
            d2 = dot2acc(A2.y, hc.y, d2); d3 = dot2acc(A3.y, hc.y, d3);
            d0 = dot2acc(A0.z, hc.z, d0); d1 = dot2acc(A1.z, hc.z, d1);
            d2 = dot2acc(A2.z, hc.z, d2); d3 = dot2acc(A3.z, hc.z, d3);
            d0 = dot2acc(A0.w, hc.w, d0); d1 = dot2acc(A1.w, hc.w, d1);
            d2 = dot2acc(A2.w, hc.w, d2); d3 = dot2acc(A3.w, hc.w, d3);
            d0 += __shfl_xor(d0, 1);  d1 += __shfl_xor(d1, 1);
            d2 += __shfl_xor(d2, 1);  d3 += __shfl_xor(d3, 1);
            d0 += __shfl_xor(d0, 2);  d1 += __shfl_xor(d1, 2);
            d2 += __shfl_xor(d2, 2);  d3 += __shfl_xor(d3, 2);
            d0 += __shfl_xor(d0, 4);  d1 += __shfl_xor(d1, 4);
            d2 += __shfl_xor(d2, 4);  d3 += __shfl_xor(d3, 4);
            // lane fl = k (k<4) finalizes slot k of its sub: 32 active lanes,
            // coalesced pay store, 32 parallel exp/atomics
            float ds = d0;
            unsigned pvs = pv0;
            if (fl == 1) { ds = d1; pvs = pv1; }
            if (fl == 2) { ds = d2; pvs = pv2; }
            if (fl == 3) { ds = d3; pvs = pv3; }
            int ss = i0 + sub + (fl << 3);
            if (fl < 4 && ss < end) {
                unsigned r = pvs >> 15;
                float ex = expf(beta * ds);
                unsigned q = (unsigned)(ex * QSCALE + 0.5f);
                pay[ss] = pvs | q;
                atomicAdd(&segsum[r], (float)q * QINV);
            }
        }
    }
}

// Fold 1/segsum into features: xw[r] = x[r] / segsum[r] (f16), overwriting
// the normalized array (sim is done with it). Grid-stride.
__global__ void xw_kernel(const uint2* __restrict__ xh2, const float* __restrict__ segsum,
                          uint2* __restrict__ xw2) {
    int stride = gridDim.x * blockDim.x;
    for (int tid = blockIdx.x * blockDim.x + threadIdx.x; tid < N_NODES * 16; tid += stride) {
        int node = tid >> 4;
        int lane = tid & 15;
        float w = fastrcp(segsum[node]);
        uint2 h = xh2[(size_t)node * 16 + lane];
        h2 ha = __builtin_bit_cast(h2, h.x);
        h2 hb = __builtin_bit_cast(h2, h.y);
        uint2 o;
        o.x = pack2h((float)ha.x * w, (float)ha.y * w);
        o.y = pack2h((float)hb.x * w, (float)hb.y * w);
        xw2[(size_t)node * 16 + lane] = o;
    }
}

// Persistent grid-stride waves, one node at a time per wave:
// out[n] = sum of q*QINV * xw[row] (f16 xw); 32 edges per iter.
__global__ void gather_kernel(const uint4* __restrict__ xw4, const unsigned* __restrict__ offs,
                              const unsigned* __restrict__ pay, float4* __restrict__ out4) {
    int lane = threadIdx.x & 63;
    int wid = (blockIdx.x * blockDim.x + threadIdx.x) >> 6;
    int nw = (gridDim.x * blockDim.x) >> 6;
    int sub = lane >> 3;
    int fl  = lane & 7;
    for (int node = wid; node < N_NODES; node += nw) {
        int start = (int)offs[node];
        int end = (int)offs[node + 1];
        float a0 = 0.f, a1 = 0.f, a2 = 0.f, a3 = 0.f;
        float a4 = 0.f, a5 = 0.f, a6 = 0.f, a7 = 0.f;
        for (int i0 = start; i0 < end; i0 += 32) {
            int idx = i0 + lane;
            if (idx > end - 1) idx = end - 1;      // duplicate last edge: dedup'd
            unsigned pvL = pay[idx];               // coalesced
            unsigned pv0 = __shfl(pvL, sub);
            unsigned pv1 = __shfl(pvL, sub + 8);
            unsigned pv2 = __shfl(pvL, sub + 16);
            unsigned pv3 = __shfl(pvL, sub + 24);
            float p0 = (i0 + sub      < end) ? (float)(pv0 & 0x7FFFu) * QINV : 0.0f;
            float p1 = (i0 + sub +  8 < end) ? (float)(pv1 & 0x7FFFu) * QINV : 0.0f;
            float p2 = (i0 + sub + 16 < end) ? (float)(pv2 & 0x7FFFu) * QINV : 0.0f;
            float p3 = (i0 + sub + 24 < end) ? (float)(pv3 & 0x7FFFu) * QINV : 0.0f;
            uint4 A0 = xw4[(size_t)(pv0 >> 15) * 8 + fl];
            uint4 A1 = xw4[(size_t)(pv1 >> 15) * 8 + fl];
            uint4 A2 = xw4[(size_t)(pv2 >> 15) * 8 + fl];
            uint4 A3 = xw4[(size_t)(pv3 >> 15) * 8 + fl];
            fma2h(A0.x, p0, a0, a1); fma2h(A1.x, p1, a0, a1);
            fma2h(A2.x, p2, a0, a1); fma2h(A3.x, p3, a0, a1);
            fma2h(A0.y, p0, a2, a3); fma2h(A1.y, p1, a2, a3);
            fma2h(A2.y, p2, a2, a3); fma2h(A3.y, p3, a2, a3);
            fma2h(A0.z, p0, a4, a5); fma2h(A1.z, p1, a4, a5);
            fma2h(A2.z, p2, a4, a5); fma2h(A3.z, p3, a4, a5);
            fma2h(A0.w, p0, a6, a7); fma2h(A1.w, p1, a6, a7);
            fma2h(A2.w, p2, a6, a7); fma2h(A3.w, p3, a6, a7);
        }
        #pragma unroll
        for (int m = 8; m <= 32; m <<= 1) {
            a0 += __shfl_xor(a0, m);
            a1 += __shfl_xor(a1, m);
            a2 += __shfl_xor(a2, m);
            a3 += __shfl_xor(a3, m);
            a4 += __shfl_xor(a4, m);
            a5 += __shfl_xor(a5, m);
            a6 += __shfl_xor(a6, m);
            a7 += __shfl_xor(a7, m);
        }
        if (sub == 0) {
            out4[(size_t)node * 16 + fl * 2]     = make_float4(a0, a1, a2, a3);
            out4[(size_t)node * 16 + fl * 2 + 1] = make_float4(a4, a5, a6, a7);
        }
    }
}

extern "C" void kernel_launch(void* const* d_in, const int* in_sizes, int n_in,
                              void* d_out, int out_size, void* d_ws, size_t ws_size,
                              hipStream_t stream) {
    const float* x      = (const float*)d_in[0];
    const int*   row    = (const int*)d_in[1];
    const int*   col    = (const int*)d_in[2];
    const float* beta_p = (const float*)d_in[3];
    const float4* x4 = (const float4*)x;
    float4* out4 = (float4*)d_out;

    // workspace layout (bytes): E4 + 2*XH + 6*S = 34.4 MB
    const size_t E4 = (size_t)N_EDGES * 4;           // 6,400,000 (16-aligned)
    const size_t XH = (size_t)N_NODES * D_FEAT * 2;  // 12,800,000 per f16 copy
    const size_t S  = 400064;                        // padded N-array stride
    char* ws = (char*)d_ws;
    unsigned* pay    = (unsigned*)ws;                    // E u32: (row<<15)|q15(ex)
    uint2*    xh2    = (uint2*)(ws + E4);                // raw f16 x (write view)
    uint2*    xn2    = (uint2*)(ws + E4 + XH);           // unit f16 x / later xw
    const uint4* xn4 = (const uint4*)(ws + E4 + XH);
    char* base2 = ws + E4 + 2 * XH;
    float*    segsum = (float*)(base2 + 0 * S);          // N f32   (zeroed by memset)
    unsigned* cnt    = (unsigned*)(base2 + 1 * S);       // N u32   (zeroed by memset)
    unsigned* incl   = (unsigned*)(base2 + 2 * S);       // N u32
    unsigned* offs   = (unsigned*)(base2 + 3 * S);       // N+1 u32
    unsigned* cursor = (unsigned*)(base2 + 4 * S);       // N u32
    unsigned* bsum   = (unsigned*)(base2 + 5 * S);       // scan block sums

    const int B = 256;
    const int nscan_blocks = (N_NODES + SCAN_B - 1) / SCAN_B;  // 391

    // zero segsum + cnt in one async memset (adjacent in layout)
    hipMemsetAsync(base2, 0, 2 * S, stream);

    const int norm_blocks = 2048;
    const int hist_blocks = 2048;
    prep_kernel<<<norm_blocks + hist_blocks, B, 0, stream>>>(x4, xh2, xn2, col, cnt, norm_blocks);

    scan1_kernel<<<nscan_blocks, SCAN_B, 0, stream>>>(cnt, incl, bsum);
    scan2_kernel<<<1, 512, 0, stream>>>(bsum, nscan_blocks);
    scan3_kernel<<<nscan_blocks + 1, SCAN_B, 0, stream>>>(cnt, incl, bsum, offs, cursor);

    place_kernel<<<2048, B, 0, stream>>>(row, col, cursor, pay);

    // persistent waves: 2048 blocks x 4 waves = 8192 waves = 32 waves/CU
    sim_csr_kernel<<<2048, B, 0, stream>>>(xn4, offs, pay, beta_p, segsum);

    xw_kernel<<<2048, B, 0, stream>>>(xh2, segsum, xn2);

    gather_kernel<<<2048, B, 0, stream>>>(xn4, offs, pay, out4);
}

// Round 6
// 359.122 us; speedup vs baseline: 1.0396x; 1.0396x over previous
//
#include <hip/hip_runtime.h>
#include <math.h>

#define N_NODES 100000
#define N_EDGES 1600000
#define D_FEAT 64
#define EPS 1e-7f
#define NPART 8
#define COLS_PER_PART (N_NODES / NPART)   // 12500
#define QSCALE 12000.0f                   // ex in (0.34, 2.9) -> q in (4116, 32767 clamped)
#define QINV (1.0f / 12000.0f)

typedef _Float16 h2 __attribute__((ext_vector_type(2)));

__device__ __forceinline__ unsigned pack2h(float a, float b) {
    h2 h;
    h.x = (_Float16)a;
    h.y = (_Float16)b;
    return __builtin_bit_cast(unsigned, h);
}

__device__ __forceinline__ float dot2acc(unsigned a, unsigned b, float c) {
#if __has_builtin(__builtin_amdgcn_fdot2)
    return __builtin_amdgcn_fdot2(__builtin_bit_cast(h2, a),
                                  __builtin_bit_cast(h2, b), c, false);
#else
    h2 ha = __builtin_bit_cast(h2, a), hb = __builtin_bit_cast(h2, b);
    return c + (float)ha.x * (float)hb.x + (float)ha.y * (float)hb.y;
#endif
}

__device__ __forceinline__ void fma2h(unsigned ab, float p, float& x, float& y) {
    h2 h = __builtin_bit_cast(h2, ab);
    x += p * (float)h.x;
    y += p * (float)h.y;
}

__device__ __forceinline__ float fastrcp(float x) {
#if __has_builtin(__builtin_amdgcn_rcpf)
    return __builtin_amdgcn_rcpf(x);
#else
    return 1.0f / x;
#endif
}

// ------- fp8 e4m3 via pure integer ops (no amdgcn fp8 builtins) -----------
// decode(byte) as f16 yields value * 2^-8 exactly (exponent remap);
// consumer pre-scales the other dot operand by 256.
__device__ __forceinline__ unsigned enc_byte(unsigned h16) {  // f16 bits -> e4m3 byte
    unsigned s = (h16 >> 8) & 0x80u;
    unsigned a = h16 & 0x7FFFu;
    unsigned e = (a < 0x2000u) ? 0u : ((a - 0x2000u + 0x40u) >> 7);
    if (e > 0x7Eu) e = 0x7Eu;        // |v|<=1 never hits; paranoia
    return s | e;
}

__device__ __forceinline__ unsigned pk4_e4m3(float a, float b, float c, float d) {
    unsigned u0 = pack2h(a, b);
    unsigned u1 = pack2h(c, d);
    return enc_byte(u0 & 0xFFFFu) | (enc_byte(u0 >> 16) << 8)
         | (enc_byte(u1 & 0xFFFFu) << 16) | (enc_byte(u1 >> 16) << 24);
}

// w = 4 e4m3 bytes; hc01/hc23 = packed f16 pairs of (hc * 256).
__device__ __forceinline__ float dot4_e4m3(unsigned w, unsigned hc01, unsigned hc23, float acc) {
    unsigned p0 = ((w & 0x0080u) << 8) | ((w & 0x007Fu) << 7)
                | ((w & 0x8000u) << 16) | ((w & 0x7F00u) << 15);
    unsigned p1 = ((w >> 8) & 0x8000u) | (((w >> 16) & 0x007Fu) << 7)
                | (w & 0x80000000u) | ((w & 0x7F000000u) >> 1);
    acc = dot2acc(p0, hc01, acc);
    acc = dot2acc(p1, hc23, acc);
    return acc;
}

__device__ __forceinline__ float dot16_e4m3(uint4 A, const unsigned* hcp) {
    float d = 0.0f;
    d = dot4_e4m3(A.x, hcp[0], hcp[1], d);
    d = dot4_e4m3(A.y, hcp[2], hcp[3], d);
    d = dot4_e4m3(A.z, hcp[4], hcp[5], d);
    d = dot4_e4m3(A.w, hcp[6], hcp[7], d);
    return d;
}

// Fused: blocks [0, norm_blocks) write raw-f16 x, unit-fp8 x, and rn=1/||x||
// (16 lanes/node); blocks [norm_blocks, ...) do the XCD-partitioned col
// histogram (int4 reads).
__global__ void prep_kernel(const float4* __restrict__ x4, uint2* __restrict__ xh2,
                            unsigned* __restrict__ xf8, float* __restrict__ nrm,
                            const int* __restrict__ col, unsigned* __restrict__ cnt,
                            int norm_blocks) {
    if ((int)blockIdx.x < norm_blocks) {
        int tid = blockIdx.x * blockDim.x + threadIdx.x;
        int node = tid >> 4;
        int lane = tid & 15;
        if (node >= N_NODES) return;
        float4 v = x4[(size_t)node * 16 + lane];
        uint2 h;
        h.x = pack2h(v.x, v.y);
        h.y = pack2h(v.z, v.w);
        xh2[(size_t)node * 16 + lane] = h;
        float s = v.x * v.x + v.y * v.y + v.z * v.z + v.w * v.w;
        s += __shfl_xor(s, 1);
        s += __shfl_xor(s, 2);
        s += __shfl_xor(s, 4);
        s += __shfl_xor(s, 8);
        float rn = rsqrtf(s);    // ||x|| > 0 a.s.; EPS negligible (||A||||B|| ~ 64)
        xf8[(size_t)node * 16 + lane] = pk4_e4m3(v.x * rn, v.y * rn, v.z * rn, v.w * rn);
        if (lane == 0) nrm[node] = rn;
    } else {
        int hb = blockIdx.x - norm_blocks;
        int part = hb & (NPART - 1);           // consistent partition->XCD bijection
        int blk = hb >> 3;
        int nblk = (gridDim.x - norm_blocks) >> 3;
        int lo = part * COLS_PER_PART;
        int hi = lo + COLS_PER_PART;
        int stride = nblk * blockDim.x;
        const int4* col4 = (const int4*)col;
        for (int e = blk * blockDim.x + threadIdx.x; e < (N_EDGES >> 2); e += stride) {
            int4 c = col4[e];
            if (c.x >= lo && c.x < hi) atomicAdd(&cnt[c.x], 1u);
            if (c.y >= lo && c.y < hi) atomicAdd(&cnt[c.y], 1u);
            if (c.z >= lo && c.z < hi) atomicAdd(&cnt[c.z], 1u);
            if (c.w >= lo && c.w < hi) atomicAdd(&cnt[c.w], 1u);
        }
    }
}

// ---- hierarchical exclusive scan over cnt[0..N) -> offs, cursor ----
#define SCAN_B 256
__global__ void scan1_kernel(const unsigned* __restrict__ cnt, unsigned* __restrict__ incl,
                             unsigned* __restrict__ bsum) {
    __shared__ unsigned sh[SCAN_B];
    int i = blockIdx.x * SCAN_B + threadIdx.x;
    unsigned v = (i < N_NODES) ? cnt[i] : 0u;
    sh[threadIdx.x] = v;
    __syncthreads();
    for (int off = 1; off < SCAN_B; off <<= 1) {
        unsigned u = (threadIdx.x >= off) ? sh[threadIdx.x - off] : 0u;
        __syncthreads();
        sh[threadIdx.x] += u;
        __syncthreads();
    }
    if (i < N_NODES) incl[i] = sh[threadIdx.x];
    if (threadIdx.x == SCAN_B - 1) bsum[blockIdx.x] = sh[SCAN_B - 1];
}

__global__ void scan2_kernel(unsigned* __restrict__ bsum, int nblocks) {
    __shared__ unsigned sh[512];
    int t = threadIdx.x;
    unsigned v = (t < nblocks) ? bsum[t] : 0u;
    sh[t] = v;
    __syncthreads();
    for (int off = 1; off < 512; off <<= 1) {
        unsigned u = (t >= off) ? sh[t - off] : 0u;
        __syncthreads();
        sh[t] += u;
        __syncthreads();
    }
    if (t < nblocks) bsum[t] = sh[t] - v;  // exclusive
}

__global__ void scan3_kernel(const unsigned* __restrict__ cnt, const unsigned* __restrict__ incl,
                             const unsigned* __restrict__ bsum, unsigned* __restrict__ offs,
                             unsigned* __restrict__ cursor) {
    int i = blockIdx.x * SCAN_B + threadIdx.x;
    if (i < N_NODES) {
        unsigned o = bsum[blockIdx.x] + incl[i] - cnt[i];
        offs[i] = o;
        cursor[i] = o;
    } else if (i == N_NODES) {
        offs[N_NODES] = N_EDGES;
    }
}

// XCD-partitioned binning: block b serves col-partition (b & 7). Writes
// pay[pos] = row << 15 (low 15 bits filled by sim_csr_kernel later).
__global__ void place_kernel(const int* __restrict__ row, const int* __restrict__ col,
                             unsigned* __restrict__ cursor, unsigned* __restrict__ pay) {
    int part = blockIdx.x & (NPART - 1);
    int blk  = blockIdx.x >> 3;
    int nblk = gridDim.x >> 3;
    int lo = part * COLS_PER_PART;
    int hi = lo + COLS_PER_PART;
    int stride = nblk * blockDim.x;
    const int4* col4 = (const int4*)col;
    for (int e4 = blk * blockDim.x + threadIdx.x; e4 < (N_EDGES >> 2); e4 += stride) {
        int4 c = col4[e4];
        int e = e4 << 2;
        if (c.x >= lo && c.x < hi) {
            unsigned pos = atomicAdd(&cursor[c.x], 1u);
            pay[pos] = (unsigned)row[e] << 15;
        }
        if (c.y >= lo && c.y < hi) {
            unsigned pos = atomicAdd(&cursor[c.y], 1u);
            pay[pos] = (unsigned)row[e + 1] << 15;
        }
        if (c.z >= lo && c.z < hi) {
            unsigned pos = atomicAdd(&cursor[c.z], 1u);
            pay[pos] = (unsigned)row[e + 2] << 15;
        }
        if (c.w >= lo && c.w < hi) {
            unsigned pos = atomicAdd(&cursor[c.w], 1u);
            pay[pos] = (unsigned)row[e + 3] << 15;
        }
    }
}

// One 64-lane wave per node c; 32 edges per iter (16 sub-groups x 2 slots).
// A-rows gathered as e4m3 (64 B/row -> 4 lane-requests/edge, table 6.4 MB
// ~ per-XCD L2); bit-decoded to f16*2^-8 and fdot2'd against hc*256*rn.
__global__ void sim_csr_kernel(const uint4* __restrict__ xf8q, const uint4* __restrict__ xh4,
                               const float* __restrict__ nrm, const unsigned* __restrict__ offs,
                               unsigned* __restrict__ pay, const float* __restrict__ beta_p,
                               float* __restrict__ segsum) {
    int gtid = blockIdx.x * blockDim.x + threadIdx.x;
    int node = gtid >> 6;
    if (node >= N_NODES) return;
    int lane = threadIdx.x & 63;
    int sub = lane >> 2;      // 0..15
    int fl  = lane & 3;       // quarter-row: 16 elems of 64
    uint4 hA = xh4[(size_t)node * 8 + fl * 2];
    uint4 hB = xh4[(size_t)node * 8 + fl * 2 + 1];
    float rs = nrm[node] * 256.0f;     // fold the 2^8 decode scale into hc
    unsigned hcp[8];
    {
        h2 t;
        t = __builtin_bit_cast(h2, hA.x); hcp[0] = pack2h((float)t.x * rs, (float)t.y * rs);
        t = __builtin_bit_cast(h2, hA.y); hcp[1] = pack2h((float)t.x * rs, (float)t.y * rs);
        t = __builtin_bit_cast(h2, hA.z); hcp[2] = pack2h((float)t.x * rs, (float)t.y * rs);
        t = __builtin_bit_cast(h2, hA.w); hcp[3] = pack2h((float)t.x * rs, (float)t.y * rs);
        t = __builtin_bit_cast(h2, hB.x); hcp[4] = pack2h((float)t.x * rs, (float)t.y * rs);
        t = __builtin_bit_cast(h2, hB.y); hcp[5] = pack2h((float)t.x * rs, (float)t.y * rs);
        t = __builtin_bit_cast(h2, hB.z); hcp[6] = pack2h((float)t.x * rs, (float)t.y * rs);
        t = __builtin_bit_cast(h2, hB.w); hcp[7] = pack2h((float)t.x * rs, (float)t.y * rs);
    }
    float beta = beta_p[0];
    int start = (int)offs[node];
    int end = (int)offs[node + 1];
    for (int i0 = start; i0 < end; i0 += 32) {
        int idx = i0 + lane;
        if (idx > end - 1) idx = end - 1;      // duplicate last edge: dedup'd
        unsigned pvL = pay[idx];               // coalesced
        unsigned pv0 = __shfl(pvL, sub);
        unsigned pv1 = __shfl(pvL, sub + 16);
        uint4 A0 = xf8q[(size_t)(pv0 >> 15) * 4 + fl];
        uint4 A1 = xf8q[(size_t)(pv1 >> 15) * 4 + fl];
        float d0 = dot16_e4m3(A0, hcp);
        float d1 = dot16_e4m3(A1, hcp);
        d0 += __shfl_xor(d0, 1);  d1 += __shfl_xor(d1, 1);
        d0 += __shfl_xor(d0, 2);  d1 += __shfl_xor(d1, 2);
        // lane fl = k (k<2) finalizes slot k of its sub: 32 active lanes,
        // coalesced pay store, 32 parallel exp/atomics
        float ds = (fl & 1) ? d1 : d0;
        unsigned pvs = (fl & 1) ? pv1 : pv0;
        int ss = i0 + ((fl & 1) << 4) + sub;
        if (fl < 2 && ss < end) {
            unsigned r = pvs >> 15;
            float ex = expf(beta * ds);
            unsigned q = (unsigned)(ex * QSCALE + 0.5f);
            if (q > 32767u) q = 32767u;        // quant noise on near-parallel rows
            pay[ss] = pvs | q;
            atomicAdd(&segsum[r], (float)q * QINV);
        }
    }
}

// Fold 1/segsum into features IN-PLACE: xw[r] = x[r] / segsum[r] (f16).
__global__ void xw_kernel(uint2* __restrict__ xw2, const float* __restrict__ segsum) {
    int tid = blockIdx.x * blockDim.x + threadIdx.x;
    int node = tid >> 4;
    int lane = tid & 15;
    if (node >= N_NODES) return;
    float w = fastrcp(segsum[node]);
    uint2 h = xw2[(size_t)node * 16 + lane];
    h2 ha = __builtin_bit_cast(h2, h.x);
    h2 hb = __builtin_bit_cast(h2, h.y);
    uint2 o;
    o.x = pack2h((float)ha.x * w, (float)ha.y * w);
    o.y = pack2h((float)hb.x * w, (float)hb.y * w);
    xw2[(size_t)node * 16 + lane] = o;
}

// One 64-lane wave per node: out[n] = sum of q*QINV * xw[row] (f16 xw);
// 32 edges per iter (8 sub-groups x 4 slots).
__global__ void gather_kernel(const uint4* __restrict__ xw4, const unsigned* __restrict__ offs,
                              const unsigned* __restrict__ pay, float4* __restrict__ out4) {
    int gtid = blockIdx.x * blockDim.x + threadIdx.x;
    int node = gtid >> 6;
    if (node >= N_NODES) return;
    int lane = threadIdx.x & 63;
    int sub = lane >> 3;
    int fl  = lane & 7;
    int start = (int)offs[node];
    int end = (int)offs[node + 1];
    float a0 = 0.f, a1 = 0.f, a2 = 0.f, a3 = 0.f;
    float a4 = 0.f, a5 = 0.f, a6 = 0.f, a7 = 0.f;
    for (int i0 = start; i0 < end; i0 += 32) {
        int idx = i0 + lane;
        if (idx > end - 1) idx = end - 1;      // duplicate last edge: dedup'd
        unsigned pvL = pay[idx];               // coalesced
        unsigned pv0 = __shfl(pvL, sub);
        unsigned pv1 = __shfl(pvL, sub + 8);
        unsigned pv2 = __shfl(pvL, sub + 16);
        unsigned pv3 = __shfl(pvL, sub + 24);
        float p0 = (i0 + sub      < end) ? (float)(pv0 & 0x7FFFu) * QINV : 0.0f;
        float p1 = (i0 + sub +  8 < end) ? (float)(pv1 & 0x7FFFu) * QINV : 0.0f;
        float p2 = (i0 + sub + 16 < end) ? (float)(pv2 & 0x7FFFu) * QINV : 0.0f;
        float p3 = (i0 + sub + 24 < end) ? (float)(pv3 & 0x7FFFu) * QINV : 0.0f;
        uint4 A0 = xw4[(size_t)(pv0 >> 15) * 8 + fl];
        uint4 A1 = xw4[(size_t)(pv1 >> 15) * 8 + fl];
        uint4 A2 = xw4[(size_t)(pv2 >> 15) * 8 + fl];
        uint4 A3 = xw4[(size_t)(pv3 >> 15) * 8 + fl];
        fma2h(A0.x, p0, a0, a1); fma2h(A1.x, p1, a0, a1);
        fma2h(A2.x, p2, a0, a1); fma2h(A3.x, p3, a0, a1);
        fma2h(A0.y, p0, a2, a3); fma2h(A1.y, p1, a2, a3);
        fma2h(A2.y, p2, a2, a3); fma2h(A3.y, p3, a2, a3);
        fma2h(A0.z, p0, a4, a5); fma2h(A1.z, p1, a4, a5);
        fma2h(A2.z, p2, a4, a5); fma2h(A3.z, p3, a4, a5);
        fma2h(A0.w, p0, a6, a7); fma2h(A1.w, p1, a6, a7);
        fma2h(A2.w, p2, a6, a7); fma2h(A3.w, p3, a6, a7);
    }
    #pragma unroll
    for (int m = 8; m <= 32; m <<= 1) {
        a0 += __shfl_xor(a0, m);
        a1 += __shfl_xor(a1, m);
        a2 += __shfl_xor(a2, m);
        a3 += __shfl_xor(a3, m);
        a4 += __shfl_xor(a4, m);
        a5 += __shfl_xor(a5, m);
        a6 += __shfl_xor(a6, m);
        a7 += __shfl_xor(a7, m);
    }
    if (sub == 0) {
        out4[(size_t)node * 16 + fl * 2]     = make_float4(a0, a1, a2, a3);
        out4[(size_t)node * 16 + fl * 2 + 1] = make_float4(a4, a5, a6, a7);
    }
}

extern "C" void kernel_launch(void* const* d_in, const int* in_sizes, int n_in,
                              void* d_out, int out_size, void* d_ws, size_t ws_size,
                              hipStream_t stream) {
    const float* x      = (const float*)d_in[0];
    const int*   row    = (const int*)d_in[1];
    const int*   col    = (const int*)d_in[2];
    const float* beta_p = (const float*)d_in[3];
    const float4* x4 = (const float4*)x;
    float4* out4 = (float4*)d_out;

    // workspace layout (bytes): E4 + XH + XF + 7*S = 28.4 MB (< 34.4 MB used by R2/R3)
    const size_t E4 = (size_t)N_EDGES * 4;           // 6,400,000 (16-aligned)
    const size_t XH = (size_t)N_NODES * D_FEAT * 2;  // 12,800,000 f16 copy (raw x -> xw)
    const size_t XF = (size_t)N_NODES * D_FEAT;      // 6,400,000 e4m3 unit copy
    const size_t S  = 400064;                        // padded N-array stride
    char* ws = (char*)d_ws;
    unsigned* pay    = (unsigned*)ws;                    // E u32: (row<<15)|q15(ex)
    uint2*    xh2    = (uint2*)(ws + E4);                // raw f16 x -> xw in-place
    const uint4* xh4 = (const uint4*)(ws + E4);
    const uint4* xw4 = (const uint4*)(ws + E4);
    unsigned* xf8    = (unsigned*)(ws + E4 + XH);        // unit e4m3 x (A side)
    const uint4* xf8q = (const uint4*)(ws + E4 + XH);
    char* base2 = ws + E4 + XH + XF;
    float*    segsum = (float*)(base2 + 0 * S);          // N f32   (zeroed by memset)
    unsigned* cnt    = (unsigned*)(base2 + 1 * S);       // N u32   (zeroed by memset)
    float*    nrm    = (float*)(base2 + 2 * S);          // N f32: rn = 1/||x||
    unsigned* incl   = (unsigned*)(base2 + 3 * S);       // N u32
    unsigned* offs   = (unsigned*)(base2 + 4 * S);       // N+1 u32
    unsigned* cursor = (unsigned*)(base2 + 5 * S);       // N u32
    unsigned* bsum   = (unsigned*)(base2 + 6 * S);       // scan block sums

    const int B = 256;
    const int nscan_blocks = (N_NODES + SCAN_B - 1) / SCAN_B;  // 391

    // zero segsum + cnt in one async memset (adjacent in layout)
    hipMemsetAsync(base2, 0, 2 * S, stream);

    const int norm_blocks = (N_NODES * 16 + B - 1) / B;   // 6250
    const int hist_blocks = 2048;
    prep_kernel<<<norm_blocks + hist_blocks, B, 0, stream>>>(x4, xh2, xf8, nrm, col, cnt,
                                                             norm_blocks);

    scan1_kernel<<<nscan_blocks, SCAN_B, 0, stream>>>(cnt, incl, bsum);
    scan2_kernel<<<1, 512, 0, stream>>>(bsum, nscan_blocks);
    scan3_kernel<<<nscan_blocks + 1, SCAN_B, 0, stream>>>(cnt, incl, bsum, offs, cursor);

    place_kernel<<<2048, B, 0, stream>>>(row, col, cursor, pay);

    int node_wave_grid = (N_NODES * 64) / B;   // 25000 blocks, 4 waves each
    sim_csr_kernel<<<node_wave_grid, B, 0, stream>>>(xf8q, xh4, nrm, offs, pay, beta_p, segsum);

    xw_kernel<<<norm_blocks, B, 0, stream>>>(xh2, segsum);

    gather_kernel<<<node_wave_grid, B, 0, stream>>>(xw4, offs, pay, out4);
}

// Round 7
// 351.838 us; speedup vs baseline: 1.0612x; 1.0207x over previous
//
#include <hip/hip_runtime.h>
#include <math.h>

#define N_NODES 100000
#define N_EDGES 1600000
#define D_FEAT 64
#define EPS 1e-7f
#define NPART 8
#define NSHARD 8
#define SPW 100032                        // padded shadow-array stride (elements)
#define COLS_PER_PART (N_NODES / NPART)   // 12500
#define QSCALE 12000.0f                   // ex in (0.34, 2.9) -> q in (4116, 32767 clamped)
#define QINV (1.0f / 12000.0f)

typedef _Float16 h2 __attribute__((ext_vector_type(2)));

__device__ __forceinline__ unsigned pack2h(float a, float b) {
    h2 h;
    h.x = (_Float16)a;
    h.y = (_Float16)b;
    return __builtin_bit_cast(unsigned, h);
}

__device__ __forceinline__ float dot2acc(unsigned a, unsigned b, float c) {
#if __has_builtin(__builtin_amdgcn_fdot2)
    return __builtin_amdgcn_fdot2(__builtin_bit_cast(h2, a),
                                  __builtin_bit_cast(h2, b), c, false);
#else
    h2 ha = __builtin_bit_cast(h2, a), hb = __builtin_bit_cast(h2, b);
    return c + (float)ha.x * (float)hb.x + (float)ha.y * (float)hb.y;
#endif
}

__device__ __forceinline__ void fma2h(unsigned ab, float p, float& x, float& y) {
    h2 h = __builtin_bit_cast(h2, ab);
    x += p * (float)h.x;
    y += p * (float)h.y;
}

__device__ __forceinline__ float fastrcp(float x) {
#if __has_builtin(__builtin_amdgcn_rcpf)
    return __builtin_amdgcn_rcpf(x);
#else
    return 1.0f / x;
#endif
}

// ------- fp8 e4m3 via pure integer ops (no amdgcn fp8 builtins) -----------
// decode(byte) as f16 yields value * 2^-8 exactly (exponent remap);
// consumer pre-scales the other dot operand by 256.
__device__ __forceinline__ unsigned enc_byte(unsigned h16) {  // f16 bits -> e4m3 byte
    unsigned s = (h16 >> 8) & 0x80u;
    unsigned a = h16 & 0x7FFFu;
    unsigned e = (a < 0x2000u) ? 0u : ((a - 0x2000u + 0x40u) >> 7);
    if (e > 0x7Eu) e = 0x7Eu;        // |v|<=1 never hits; paranoia
    return s | e;
}

__device__ __forceinline__ unsigned pk4_e4m3(float a, float b, float c, float d) {
    unsigned u0 = pack2h(a, b);
    unsigned u1 = pack2h(c, d);
    return enc_byte(u0 & 0xFFFFu) | (enc_byte(u0 >> 16) << 8)
         | (enc_byte(u1 & 0xFFFFu) << 16) | (enc_byte(u1 >> 16) << 24);
}

// w = 4 e4m3 bytes; hc01/hc23 = packed f16 pairs of (hc * 256).
__device__ __forceinline__ float dot4_e4m3(unsigned w, unsigned hc01, unsigned hc23, float acc) {
    unsigned p0 = ((w & 0x0080u) << 8) | ((w & 0x007Fu) << 7)
                | ((w & 0x8000u) << 16) | ((w & 0x7F00u) << 15);
    unsigned p1 = ((w >> 8) & 0x8000u) | (((w >> 16) & 0x007Fu) << 7)
                | (w & 0x80000000u) | ((w & 0x7F000000u) >> 1);
    acc = dot2acc(p0, hc01, acc);
    acc = dot2acc(p1, hc23, acc);
    return acc;
}

__device__ __forceinline__ float dot16_e4m3(uint4 A, const unsigned* hcp) {
    float d = 0.0f;
    d = dot4_e4m3(A.x, hcp[0], hcp[1], d);
    d = dot4_e4m3(A.y, hcp[2], hcp[3], d);
    d = dot4_e4m3(A.z, hcp[4], hcp[5], d);
    d = dot4_e4m3(A.w, hcp[6], hcp[7], d);
    return d;
}

// Fused: blocks [0, norm_blocks) write raw-f16 x, unit-fp8 x, and rn=1/||x||
// (16 lanes/node); blocks [norm_blocks, ...) do the XCD-partitioned col
// histogram into 8 SHARDED count arrays (contention/line / 8).
__global__ void prep_kernel(const float4* __restrict__ x4, uint2* __restrict__ xh2,
                            unsigned* __restrict__ xf8, float* __restrict__ nrm,
                            const int* __restrict__ col, unsigned* __restrict__ cnt8,
                            int norm_blocks) {
    if ((int)blockIdx.x < norm_blocks) {
        int tid = blockIdx.x * blockDim.x + threadIdx.x;
        int node = tid >> 4;
        int lane = tid & 15;
        if (node >= N_NODES) return;
        float4 v = x4[(size_t)node * 16 + lane];
        uint2 h;
        h.x = pack2h(v.x, v.y);
        h.y = pack2h(v.z, v.w);
        xh2[(size_t)node * 16 + lane] = h;
        float s = v.x * v.x + v.y * v.y + v.z * v.z + v.w * v.w;
        s += __shfl_xor(s, 1);
        s += __shfl_xor(s, 2);
        s += __shfl_xor(s, 4);
        s += __shfl_xor(s, 8);
        float rn = rsqrtf(s);    // ||x|| > 0 a.s.; EPS negligible (||A||||B|| ~ 64)
        xf8[(size_t)node * 16 + lane] = pk4_e4m3(v.x * rn, v.y * rn, v.z * rn, v.w * rn);
        if (lane == 0) nrm[node] = rn;
    } else {
        int hb = blockIdx.x - norm_blocks;
        int part = hb & (NPART - 1);           // consistent partition->XCD bijection
        int blk = hb >> 3;
        int nblk = (gridDim.x - norm_blocks) >> 3;
        unsigned* cs = cnt8 + (size_t)(blk & (NSHARD - 1)) * SPW;  // shard by chunk
        int lo = part * COLS_PER_PART;
        int hi = lo + COLS_PER_PART;
        int stride = nblk * blockDim.x;
        const int4* col4 = (const int4*)col;
        for (int e = blk * blockDim.x + threadIdx.x; e < (N_EDGES >> 2); e += stride) {
            int4 c = col4[e];
            if (c.x >= lo && c.x < hi) atomicAdd(&cs[c.x], 1u);
            if (c.y >= lo && c.y < hi) atomicAdd(&cs[c.y], 1u);
            if (c.z >= lo && c.z < hi) atomicAdd(&cs[c.z], 1u);
            if (c.w >= lo && c.w < hi) atomicAdd(&cs[c.w], 1u);
        }
    }
}

// ---- hierarchical exclusive scan over summed shard counts -> offs, cursors ----
#define SCAN_B 256
__global__ void scan1_kernel(const unsigned* __restrict__ cnt8, unsigned* __restrict__ incl,
                             unsigned* __restrict__ bsum) {
    __shared__ unsigned sh[SCAN_B];
    int i = blockIdx.x * SCAN_B + threadIdx.x;
    unsigned v = 0u;
    if (i < N_NODES) {
        #pragma unroll
        for (int k = 0; k < NSHARD; k++) v += cnt8[(size_t)k * SPW + i];
    }
    sh[threadIdx.x] = v;
    __syncthreads();
    for (int off = 1; off < SCAN_B; off <<= 1) {
        unsigned u = (threadIdx.x >= off) ? sh[threadIdx.x - off] : 0u;
        __syncthreads();
        sh[threadIdx.x] += u;
        __syncthreads();
    }
    if (i < N_NODES) incl[i] = sh[threadIdx.x];
    if (threadIdx.x == SCAN_B - 1) bsum[blockIdx.x] = sh[SCAN_B - 1];
}

__global__ void scan2_kernel(unsigned* __restrict__ bsum, int nblocks) {
    __shared__ unsigned sh[512];
    int t = threadIdx.x;
    unsigned v = (t < nblocks) ? bsum[t] : 0u;
    sh[t] = v;
    __syncthreads();
    for (int off = 1; off < 512; off <<= 1) {
        unsigned u = (t >= off) ? sh[t - off] : 0u;
        __syncthreads();
        sh[t] += u;
        __syncthreads();
    }
    if (t < nblocks) bsum[t] = sh[t] - v;  // exclusive
}

// Converts cnt8 IN PLACE into per-shard cursors: cursor8[k][c] = offs[c] +
// sum_{k'<k} cnt8[k'][c]. Each (c, shard) owns a disjoint sub-segment of
// col c's CSR range, so place needs no cross-shard uniqueness.
__global__ void scan3_kernel(unsigned* __restrict__ cnt8, const unsigned* __restrict__ incl,
                             const unsigned* __restrict__ bsum, unsigned* __restrict__ offs) {
    int i = blockIdx.x * SCAN_B + threadIdx.x;
    if (i < N_NODES) {
        unsigned c8[NSHARD];
        unsigned tot = 0u;
        #pragma unroll
        for (int k = 0; k < NSHARD; k++) { c8[k] = cnt8[(size_t)k * SPW + i]; tot += c8[k]; }
        unsigned o = bsum[blockIdx.x] + incl[i] - tot;   // exclusive offset
        offs[i] = o;
        unsigned acc = o;
        #pragma unroll
        for (int k = 0; k < NSHARD; k++) { cnt8[(size_t)k * SPW + i] = acc; acc += c8[k]; }
    } else if (i == N_NODES) {
        offs[N_NODES] = N_EDGES;
    }
}

// XCD-partitioned binning with SHARDED cursors (same edge->block mapping as
// the histogram, so counts match cursors exactly). pay[pos] = row << 15.
__global__ void place_kernel(const int* __restrict__ row, const int* __restrict__ col,
                             unsigned* __restrict__ cur8, unsigned* __restrict__ pay) {
    int part = blockIdx.x & (NPART - 1);
    int blk  = blockIdx.x >> 3;
    int nblk = gridDim.x >> 3;
    unsigned* cs = cur8 + (size_t)(blk & (NSHARD - 1)) * SPW;
    int lo = part * COLS_PER_PART;
    int hi = lo + COLS_PER_PART;
    int stride = nblk * blockDim.x;
    const int4* col4 = (const int4*)col;
    for (int e4 = blk * blockDim.x + threadIdx.x; e4 < (N_EDGES >> 2); e4 += stride) {
        int4 c = col4[e4];
        int e = e4 << 2;
        if (c.x >= lo && c.x < hi) {
            unsigned pos = atomicAdd(&cs[c.x], 1u);
            pay[pos] = (unsigned)row[e] << 15;
        }
        if (c.y >= lo && c.y < hi) {
            unsigned pos = atomicAdd(&cs[c.y], 1u);
            pay[pos] = (unsigned)row[e + 1] << 15;
        }
        if (c.z >= lo && c.z < hi) {
            unsigned pos = atomicAdd(&cs[c.z], 1u);
            pay[pos] = (unsigned)row[e + 2] << 15;
        }
        if (c.w >= lo && c.w < hi) {
            unsigned pos = atomicAdd(&cs[c.w], 1u);
            pay[pos] = (unsigned)row[e + 3] << 15;
        }
    }
}

// One 64-lane wave per node c; 32 edges per iter (16 sub-groups x 2 slots).
// A-rows gathered as e4m3; segsum atomics SHARDED 8x by blockIdx&7.
__global__ void sim_csr_kernel(const uint4* __restrict__ xf8q, const uint4* __restrict__ xh4,
                               const float* __restrict__ nrm, const unsigned* __restrict__ offs,
                               unsigned* __restrict__ pay, const float* __restrict__ beta_p,
                               float* __restrict__ segsum8) {
    int gtid = blockIdx.x * blockDim.x + threadIdx.x;
    int node = gtid >> 6;
    if (node >= N_NODES) return;
    float* seg = segsum8 + (size_t)(blockIdx.x & (NSHARD - 1)) * SPW;
    int lane = threadIdx.x & 63;
    int sub = lane >> 2;      // 0..15
    int fl  = lane & 3;       // quarter-row: 16 elems of 64
    uint4 hA = xh4[(size_t)node * 8 + fl * 2];
    uint4 hB = xh4[(size_t)node * 8 + fl * 2 + 1];
    float rs = nrm[node] * 256.0f;     // fold the 2^8 decode scale into hc
    unsigned hcp[8];
    {
        h2 t;
        t = __builtin_bit_cast(h2, hA.x); hcp[0] = pack2h((float)t.x * rs, (float)t.y * rs);
        t = __builtin_bit_cast(h2, hA.y); hcp[1] = pack2h((float)t.x * rs, (float)t.y * rs);
        t = __builtin_bit_cast(h2, hA.z); hcp[2] = pack2h((float)t.x * rs, (float)t.y * rs);
        t = __builtin_bit_cast(h2, hA.w); hcp[3] = pack2h((float)t.x * rs, (float)t.y * rs);
        t = __builtin_bit_cast(h2, hB.x); hcp[4] = pack2h((float)t.x * rs, (float)t.y * rs);
        t = __builtin_bit_cast(h2, hB.y); hcp[5] = pack2h((float)t.x * rs, (float)t.y * rs);
        t = __builtin_bit_cast(h2, hB.z); hcp[6] = pack2h((float)t.x * rs, (float)t.y * rs);
        t = __builtin_bit_cast(h2, hB.w); hcp[7] = pack2h((float)t.x * rs, (float)t.y * rs);
    }
    float beta = beta_p[0];
    int start = (int)offs[node];
    int end = (int)offs[node + 1];
    for (int i0 = start; i0 < end; i0 += 32) {
        int idx = i0 + lane;
        if (idx > end - 1) idx = end - 1;      // duplicate last edge: dedup'd
        unsigned pvL = pay[idx];               // coalesced
        unsigned pv0 = __shfl(pvL, sub);
        unsigned pv1 = __shfl(pvL, sub + 16);
        uint4 A0 = xf8q[(size_t)(pv0 >> 15) * 4 + fl];
        uint4 A1 = xf8q[(size_t)(pv1 >> 15) * 4 + fl];
        float d0 = dot16_e4m3(A0, hcp);
        float d1 = dot16_e4m3(A1, hcp);
        d0 += __shfl_xor(d0, 1);  d1 += __shfl_xor(d1, 1);
        d0 += __shfl_xor(d0, 2);  d1 += __shfl_xor(d1, 2);
        // lane fl = k (k<2) finalizes slot k of its sub: 32 active lanes,
        // coalesced pay store, 32 parallel exp/atomics
        float ds = (fl & 1) ? d1 : d0;
        unsigned pvs = (fl & 1) ? pv1 : pv0;
        int ss = i0 + ((fl & 1) << 4) + sub;
        if (fl < 2 && ss < end) {
            unsigned r = pvs >> 15;
            float ex = expf(beta * ds);
            unsigned q = (unsigned)(ex * QSCALE + 0.5f);
            if (q > 32767u) q = 32767u;        // quant noise on near-parallel rows
            pay[ss] = pvs | q;
            atomicAdd(&seg[r], (float)q * QINV);
        }
    }
}

// Fold 1/sum(segsum8[k]) into features IN-PLACE: xw[r] = x[r] / segsum[r].
// 16 lanes/node: lanes 0-7 read one shard each; 4 shuffles broadcast the sum.
__global__ void xw_kernel(uint2* __restrict__ xw2, const float* __restrict__ segsum8) {
    int tid = blockIdx.x * blockDim.x + threadIdx.x;
    int node = tid >> 4;
    int il = tid & 15;
    if (node >= N_NODES) return;
    float s = (il < NSHARD) ? segsum8[(size_t)il * SPW + node] : 0.0f;
    s += __shfl_xor(s, 8);
    s += __shfl_xor(s, 4);
    s += __shfl_xor(s, 2);
    s += __shfl_xor(s, 1);
    float w = fastrcp(s);
    uint2 h = xw2[(size_t)node * 16 + il];
    h2 ha = __builtin_bit_cast(h2, h.x);
    h2 hb = __builtin_bit_cast(h2, h.y);
    uint2 o;
    o.x = pack2h((float)ha.x * w, (float)ha.y * w);
    o.y = pack2h((float)hb.x * w, (float)hb.y * w);
    xw2[(size_t)node * 16 + il] = o;
}

// One 64-lane wave per node: out[n] = sum of q*QINV * xw[row] (f16 xw);
// 32 edges per iter (8 sub-groups x 4 slots).
__global__ void gather_kernel(const uint4* __restrict__ xw4, const unsigned* __restrict__ offs,
                              const unsigned* __restrict__ pay, float4* __restrict__ out4) {
    int gtid = blockIdx.x * blockDim.x + threadIdx.x;
    int node = gtid >> 6;
    if (node >= N_NODES) return;
    int lane = threadIdx.x & 63;
    int sub = lane >> 3;
    int fl  = lane & 7;
    int start = (int)offs[node];
    int end = (int)offs[node + 1];
    float a0 = 0.f, a1 = 0.f, a2 = 0.f, a3 = 0.f;
    float a4 = 0.f, a5 = 0.f, a6 = 0.f, a7 = 0.f;
    for (int i0 = start; i0 < end; i0 += 32) {
        int idx = i0 + lane;
        if (idx > end - 1) idx = end - 1;      // duplicate last edge: dedup'd
        unsigned pvL = pay[idx];               // coalesced
        unsigned pv0 = __shfl(pvL, sub);
        unsigned pv1 = __shfl(pvL, sub + 8);
        unsigned pv2 = __shfl(pvL, sub + 16);
        unsigned pv3 = __shfl(pvL, sub + 24);
        float p0 = (i0 + sub      < end) ? (float)(pv0 & 0x7FFFu) * QINV : 0.0f;
        float p1 = (i0 + sub +  8 < end) ? (float)(pv1 & 0x7FFFu) * QINV : 0.0f;
        float p2 = (i0 + sub + 16 < end) ? (float)(pv2 & 0x7FFFu) * QINV : 0.0f;
        float p3 = (i0 + sub + 24 < end) ? (float)(pv3 & 0x7FFFu) * QINV : 0.0f;
        uint4 A0 = xw4[(size_t)(pv0 >> 15) * 8 + fl];
        uint4 A1 = xw4[(size_t)(pv1 >> 15) * 8 + fl];
        uint4 A2 = xw4[(size_t)(pv2 >> 15) * 8 + fl];
        uint4 A3 = xw4[(size_t)(pv3 >> 15) * 8 + fl];
        fma2h(A0.x, p0, a0, a1); fma2h(A1.x, p1, a0, a1);
        fma2h(A2.x, p2, a0, a1); fma2h(A3.x, p3, a0, a1);
        fma2h(A0.y, p0, a2, a3); fma2h(A1.y, p1, a2, a3);
        fma2h(A2.y, p2, a2, a3); fma2h(A3.y, p3, a2, a3);
        fma2h(A0.z, p0, a4, a5); fma2h(A1.z, p1, a4, a5);
        fma2h(A2.z, p2, a4, a5); fma2h(A3.z, p3, a4, a5);
        fma2h(A0.w, p0, a6, a7); fma2h(A1.w, p1, a6, a7);
        fma2h(A2.w, p2, a6, a7); fma2h(A3.w, p3, a6, a7);
    }
    #pragma unroll
    for (int m = 8; m <= 32; m <<= 1) {
        a0 += __shfl_xor(a0, m);
        a1 += __shfl_xor(a1, m);
        a2 += __shfl_xor(a2, m);
        a3 += __shfl_xor(a3, m);
        a4 += __shfl_xor(a4, m);
        a5 += __shfl_xor(a5, m);
        a6 += __shfl_xor(a6, m);
        a7 += __shfl_xor(a7, m);
    }
    if (sub == 0) {
        out4[(size_t)node * 16 + fl * 2]     = make_float4(a0, a1, a2, a3);
        out4[(size_t)node * 16 + fl * 2 + 1] = make_float4(a4, a5, a6, a7);
    }
}

extern "C" void kernel_launch(void* const* d_in, const int* in_sizes, int n_in,
                              void* d_out, int out_size, void* d_ws, size_t ws_size,
                              hipStream_t stream) {
    const float* x      = (const float*)d_in[0];
    const int*   row    = (const int*)d_in[1];
    const int*   col    = (const int*)d_in[2];
    const float* beta_p = (const float*)d_in[3];
    const float4* x4 = (const float4*)x;
    float4* out4 = (float4*)d_out;

    // workspace layout (bytes): E4 + XH + XF + 20*S = 33.6 MB (< 34.4 MB proven R2/R3)
    const size_t E4 = (size_t)N_EDGES * 4;           // 6,400,000 (16-aligned)
    const size_t XH = (size_t)N_NODES * D_FEAT * 2;  // 12,800,000 f16 copy (raw x -> xw)
    const size_t XF = (size_t)N_NODES * D_FEAT;      // 6,400,000 e4m3 unit copy
    const size_t S  = (size_t)SPW * 4;               // 400,128 B shadow stride
    char* ws = (char*)d_ws;
    unsigned* pay    = (unsigned*)ws;                    // E u32: (row<<15)|q15(ex)
    uint2*    xh2    = (uint2*)(ws + E4);                // raw f16 x -> xw in-place
    const uint4* xh4 = (const uint4*)(ws + E4);
    const uint4* xw4 = (const uint4*)(ws + E4);
    unsigned* xf8    = (unsigned*)(ws + E4 + XH);        // unit e4m3 x (A side)
    const uint4* xf8q = (const uint4*)(ws + E4 + XH);
    char* base2 = ws + E4 + XH + XF;
    float*    segsum8 = (float*)(base2);                 // 8 shards x SPW f32 (memset)
    unsigned* cnt8    = (unsigned*)(base2 + 8 * S);      // 8 shards x SPW u32 (memset) -> cursors
    float*    nrm     = (float*)(base2 + 16 * S);        // N f32: rn = 1/||x||
    unsigned* incl    = (unsigned*)(base2 + 17 * S);     // N u32
    unsigned* offs    = (unsigned*)(base2 + 18 * S);     // N+1 u32
    unsigned* bsum    = (unsigned*)(base2 + 19 * S);     // scan block sums

    const int B = 256;
    const int nscan_blocks = (N_NODES + SCAN_B - 1) / SCAN_B;  // 391

    // zero segsum8 + cnt8 in one async memset (adjacent, 16*S = 6.4 MB)
    hipMemsetAsync(base2, 0, 16 * S, stream);

    const int norm_blocks = (N_NODES * 16 + B - 1) / B;   // 6250
    const int hist_blocks = 2048;
    prep_kernel<<<norm_blocks + hist_blocks, B, 0, stream>>>(x4, xh2, xf8, nrm, col, cnt8,
                                                             norm_blocks);

    scan1_kernel<<<nscan_blocks, SCAN_B, 0, stream>>>(cnt8, incl, bsum);
    scan2_kernel<<<1, 512, 0, stream>>>(bsum, nscan_blocks);
    scan3_kernel<<<nscan_blocks + 1, SCAN_B, 0, stream>>>(cnt8, incl, bsum, offs);

    place_kernel<<<2048, B, 0, stream>>>(row, col, cnt8, pay);

    int node_wave_grid = (N_NODES * 64) / B;   // 25000 blocks, 4 waves each
    sim_csr_kernel<<<node_wave_grid, B, 0, stream>>>(xf8q, xh4, nrm, offs, pay, beta_p, segsum8);

    xw_kernel<<<norm_blocks, B, 0, stream>>>(xh2, segsum8);

    gather_kernel<<<node_wave_grid, B, 0, stream>>>(xw4, offs, pay, out4);
}